// Round 1
// 59.851 us; speedup vs baseline: 1.0098x; 1.0098x over previous
//
#include <hip/hip_runtime.h>
#include <hip/hip_bf16.h>

// EPG CPMG echo-train simulation. B=256 voxels, NPC=40 compartments, 32 echoes,
// state dim 97 = 1 + 32*3.
//
// ROUND 6: DPP lane shifts. Round 5's width-16 __shfl compiles to
// ds_bpermute_b32 -- an LDS-pipe round trip (~60-120 cyc exposed latency per
// echo, lgkmcnt waits) that 2.5 waves/SIMD cannot hide; 4 of them gate every
// one of the 32 serial echo steps. CDNA DPP row ops act on exactly 16-lane
// rows, which align 1:1 with our lanes-per-compartment groups:
//   row_shr:1 (0x111): result[j] = src[j-1]   (lane 0 invalid)
//   row_shl:1 (0x101): result[j] = src[j+1]   (lane 15 invalid)
// v_mov_b32_dpp runs in the VALU (~2 cyc), no LDS pipe. DPP edge semantics
// absorb the boundary selects for free:
//   - bound_ctrl=0 keeps the OLD operand at invalid lanes -> lane-0 "own Fm0"
//     and "own f0" injections need no cndmask;
//   - bound_ctrl=1 zero-fills invalid lanes -> lane-15 Fm=0 needs no cndmask.
// Per-echo body is now pure VALU: 4 DPP + 1 mul + 18 FMA. Recurrence
// arithmetic is bit-identical to round 5 (absmax must stay 0.00390625).
//
// Lane map (j = lane-in-compartment 0..15): holds blocks 2j, 2j+1:
//   Fp0=v[1+6j] Fm0=v[2+6j] Z0=v[3+6j]; Fp1=v[4+6j] Fm1=v[5+6j] Z1=v[6+6j];
//   f0=v[0] lives in lane 0 (consumed locally: Fp1_new = f0_old).
// Telescoped update (round 3 algebra): v <- T d^2 S^2 v, H_k = e2 * v[2].
//   Fp_new[2j,2j+1] = lane j-1's (Fp0,Fp1);  lane0: Fp0=own Fm0, Fp1=own f0
//   Fm_new[2j,2j+1] = lane j+1's (Fm0,Fm1);  lane15: 0,0
//   f0_new = e2^2 * (lane1's Fm0)
//   emit H_e = e2 * Fm0 @ lane0 (pre-update), weighted.
//
// Epilogue: Hs rows padded to 44 floats (176 B, 16B-multiple) so one wave can
// reduce each echo row with 10x ds_read_b128 instead of 40 scalar reads.
//
// DTYPES (rounds 0-2 forensics): inputs f32, output f32; runtime check kept.
//
// NOTE: timed iteration includes a harness ~39us / 268MB workspace re-poison
// fill (rocprof top-5 is all fillBufferAligned); that is the floor for dur_us.

#define NB 256
#define NPC 40
#define NECH 32
#define LPC 16              // lanes per compartment
#define TPB (NPC * LPC)     // 640 threads = 10 waves

#define DPP_ROW_SHL1 0x101  // result[j] = src[j+1] within 16-lane row
#define DPP_ROW_SHR1 0x111  // result[j] = src[j-1] within 16-lane row

// shift with zero-fill at invalid lanes (bound_ctrl=1)
template <int CTRL>
__device__ __forceinline__ float dpp_shift_fill0(float x) {
    return __int_as_float(__builtin_amdgcn_update_dpp(
        0, __float_as_int(x), CTRL, 0xF, 0xF, true));
}
// shift keeping `oldv` at invalid lanes (bound_ctrl=0)
template <int CTRL>
__device__ __forceinline__ float dpp_shift_old(float oldv, float x) {
    return __int_as_float(__builtin_amdgcn_update_dpp(
        __float_as_int(oldv), __float_as_int(x), CTRL, 0xF, 0xF, false));
}

__device__ __forceinline__ float bf16_at(const void* p, int i) {
    return __bfloat162float(((const __hip_bfloat16*)p)[i]);
}
__device__ __forceinline__ float f32_at(const void* p, int i) {
    return ((const float*)p)[i];
}

__global__ __launch_bounds__(TPB, 1) void epg_kernel(
    const void* __restrict__ refoc,
    const void* __restrict__ t2,
    const void* __restrict__ wts,
    float* __restrict__ out)
{
    const int b   = blockIdx.x;
    const int tid = threadIdx.x;
    const int c   = tid >> 4;   // compartment 0..39
    const int j   = tid & 15;   // lane-in-compartment 0..15
    __shared__ __align__(16) float Hs[NECH][NPC + 4];  // +4 pad: 176B rows, b128-aligned

    // ---- runtime input-dtype check (wave-uniform; expected: f32) ----
    bool in_f32 = false;
    #pragma unroll
    for (int i = 0; i < 32; i += 2) {
        const float v = bf16_at(t2, i);
        if (!(v >= 9.0f && v <= 2100.0f)) in_f32 = true;
    }

    const float adeg = in_f32 ? f32_at(refoc, b) : bf16_at(refoc, b);
    float t2v = in_f32 ? f32_at(t2,  b * NPC + c) : bf16_at(t2,  b * NPC + c);
    const float wt = in_f32 ? f32_at(wts, b * NPC + c) : bf16_at(wts, b * NPC + c);
    t2v = fminf(fmaxf(t2v, 1.0f), 1.0e6f);  // NaN/inf-proofing

    const float alpha = adeg * 0.017453292519943295f;  // deg->rad
    const float sh = sinf(0.5f * alpha);   // sin(alpha_exc)
    const float ch = cosf(0.5f * alpha);
    const float sA = sinf(alpha);
    const float cA = cosf(alpha);
    const float c2 = ch * ch;
    const float s2 = sh * sh;
    const float e12 = 0.9900498337491681f;   // exp(-10/1000) = e1^2
    const float e2  = expf(-5.0f / t2v);     // exp(-tau/T2), tau = TAU/2 = 5
    const float e22 = e2 * e2;

    // T with d^2 folded in (transverse cols *e2^2, Z col *e1^2)
    const float M11 = c2 * e22;
    const float M12 = s2 * e22;
    const float M13 = sA * e12;
    const float M31 = 0.5f * sA * e22;
    const float M33 = cA * e12;
    const float we  = wt * e2;  // echo emit factor

    // v_1 = T d S x0 (closed form): only block 0 and v[0] nonzero.
    float Fp0 = 0.0f, Fp1 = 0.0f, Fm0 = 0.0f, Fm1 = 0.0f, Z0 = 0.0f, Z1 = 0.0f;
    float f0 = 0.0f;
    if (j == 0) {
        const float esh = e2 * sh;
        Fp0 = c2 * esh;
        Fm0 = s2 * esh;
        Z0  = -0.5f * sA * esh;
        f0  = e2 * ch;
    }

    #pragma unroll
    for (int e = 0; e < NECH; ++e) {
        if (j == 0) Hs[e][c] = we * Fm0;  // H_{e+1} = e2 * v[2], weighted
        if (e == NECH - 1) break;

        // ---- shift S^2 via DPP row ops (16-lane rows == compartments) ----
        // reads all use PRE-update register values; edge lanes handled by
        // DPP old-operand (row_shr) / zero-fill (row_shl).
        const float nFp0 = dpp_shift_old<DPP_ROW_SHR1>(Fm0, Fp0); // lane0: own Fm0
        const float nFp1 = dpp_shift_old<DPP_ROW_SHR1>(f0,  Fp1); // lane0: own f0
        const float nFm0 = dpp_shift_fill0<DPP_ROW_SHL1>(Fm0);    // lane15: 0
        const float nFm1 = dpp_shift_fill0<DPP_ROW_SHL1>(Fm1);    // lane15: 0
        f0 = e22 * nFm0;  // meaningful in lane 0 only (= e2^2 * new v[2])

        // ---- T with folded d^2 on this lane's two 3x3 blocks ----
        Fp0 = M11 * nFp0 + M12 * nFm0 + M13 * Z0;
        Fm0 = M12 * nFp0 + M11 * nFm0 - M13 * Z0;
        Z0  = M31 * (nFm0 - nFp0) + M33 * Z0;
        Fp1 = M11 * nFp1 + M12 * nFm1 + M13 * Z1;
        Fm1 = M12 * nFp1 + M11 * nFm1 - M13 * Z1;
        Z1  = M31 * (nFm1 - nFp1) + M33 * Z1;
    }

    __syncthreads();

    // First wave reduces over compartments; lanes 32..63 duplicate echoes
    // 0..31 so the __shfl broadcast of echo 0 is wave-uniform.
    if (tid < 64) {
        const int e = tid & 31;
        const float4* __restrict__ row = reinterpret_cast<const float4*>(&Hs[e][0]);
        float sum = 0.0f;
        #pragma unroll
        for (int k = 0; k < NPC / 4; ++k) {   // 10 x ds_read_b128 = 40 floats
            const float4 v = row[k];
            sum += (v.x + v.y) + (v.z + v.w);
        }
        const float sum0 = __shfl(sum, 0, 64);  // echo-0 sum (lane 0)
        if (tid < NECH) out[b * NECH + tid] = sum / sum0;
    }
}

extern "C" void kernel_launch(void* const* d_in, const int* in_sizes, int n_in,
                              void* d_out, int out_size, void* d_ws, size_t ws_size,
                              hipStream_t stream) {
    const void* refoc = d_in[0];  // (256,)    refocusing angle, degrees, f32
    const void* t2s   = d_in[1];  // (256,40)  T2 values, ms, f32
    const void* wts   = d_in[2];  // (256,40)  compartment weights, f32
    float* out = (float*)d_out;   // (256,32)  f32
    epg_kernel<<<NB, TPB, 0, stream>>>(refoc, t2s, wts, out);
}